// Round 16
// baseline (2463.710 us; speedup 1.0000x reference)
//
#include <hip/hip_runtime.h>

#define T_TOKENS 4096
#define DIM      1024
#define HID      4096
#define NE       8
#define TOPK     2
#define MAXT128  72   // sum_e ceil(cnt_e/128) <= 8192/128 + 7 = 71

#define PREP_BLOCKS (T_TOKENS / 4)                  // 1024
#define TC_BLOCKS   (NE * (DIM / 64) * (HID / 64))  // 8192 per weight matrix
#define MEGA_BLOCKS (MAXT128 * 32 + TC_BLOCKS + MAXT128 * 16)  // 11648
#define SMEM_BYTES  33792                           // GEMM: 16K+16K+512+512
#define TC_SMEM     9216                            // 64x72x2 transconv tile
#define Q_STRIDE    2048                            // per-XCD queue capacity

typedef __attribute__((ext_vector_type(8))) short short8;
typedef __attribute__((ext_vector_type(4))) float f32x4;
typedef __attribute__((ext_vector_type(4))) unsigned short u16x4;

__device__ __forceinline__ unsigned short f2bf(float f) {
    unsigned int u = __builtin_bit_cast(unsigned int, f);
    u += 0x7fffu + ((u >> 16) & 1u);
    return (unsigned short)(u >> 16);
}

__device__ __forceinline__ void gload16(const void* g, void* l) {
    __builtin_amdgcn_global_load_lds(
        (const __attribute__((address_space(1))) unsigned int*)g,
        (__attribute__((address_space(3))) unsigned int*)l, 16, 0, 0);
}

// ------- prep body: router (top2 softmax gate scatter) + x->bf16 + out=x -----
__device__ __forceinline__ void prep_body(
    const float* __restrict__ x, const float* __restrict__ Wg,
    const float* __restrict__ bg, int* __restrict__ counts,
    int* __restrict__ rowlist, float* __restrict__ gatelist,
    unsigned short* __restrict__ xb, float* __restrict__ out, int bid) {
    const int wid  = threadIdx.x >> 6;
    const int lane = threadIdx.x & 63;
    const int t = bid * 4 + wid;
    float acc[NE];
#pragma unroll
    for (int e = 0; e < NE; ++e) acc[e] = 0.f;
    const float* xr = x + (size_t)t * DIM;
    for (int d = lane; d < DIM; d += 64) {
        const float xv = xr[d];
        const float* wr = Wg + (size_t)d * NE;
#pragma unroll
        for (int e = 0; e < NE; ++e) acc[e] += xv * wr[e];
    }
#pragma unroll
    for (int off = 32; off > 0; off >>= 1) {
#pragma unroll
        for (int e = 0; e < NE; ++e) acc[e] += __shfl_xor(acc[e], off);
    }
    if (lane == 0) {
        float lg[NE];
#pragma unroll
        for (int e = 0; e < NE; ++e) lg[e] = acc[e] + bg[e];
        int i1 = 0; float v1 = lg[0];
#pragma unroll
        for (int e = 1; e < NE; ++e) if (lg[e] > v1) { v1 = lg[e]; i1 = e; }
        int i2 = -1; float v2 = -3.4e38f;
#pragma unroll
        for (int e = 0; e < NE; ++e) if (e != i1 && lg[e] > v2) { v2 = lg[e]; i2 = e; }
        const float ex = expf(v2 - v1);            // v1 >= v2
        const float g1 = 1.f / (1.f + ex);
        const float g2 = ex / (1.f + ex);
        int p1 = atomicAdd(&counts[i1], 1);
        rowlist[i1 * T_TOKENS + p1] = t * 2;
        gatelist[i1 * T_TOKENS + p1] = g1;
        int p2 = atomicAdd(&counts[i2], 1);
        rowlist[i2 * T_TOKENS + p2] = t * 2 + 1;
        gatelist[i2 * T_TOKENS + p2] = g2;
    }
    const float4* xr4 = (const float4*)xr;
    float4* o4 = (float4*)(out + (size_t)t * DIM);
    ushort4* xb4 = (ushort4*)(xb + (size_t)t * DIM);
#pragma unroll
    for (int p = 0; p < 4; ++p) {
        const int i = p * 64 + lane;
        const float4 v = xr4[i];
        o4[i] = v;
        ushort4 o;
        o.x = f2bf(v.x); o.y = f2bf(v.y); o.z = f2bf(v.z); o.w = f2bf(v.w);
        xb4[i] = o;
    }
}

// --- transconv body: W [e][K][N] f32 -> Wb [e][N][K] bf16, nontemporal reads -
template <int K, int N>
__device__ __forceinline__ void transconv_body(const float* __restrict__ W,
                                               unsigned short* __restrict__ Wb,
                                               int lin, char* smem) {
    const int nb = (lin % (N / 64)) * 64;
    const int k0 = ((lin / (N / 64)) % (K / 64)) * 64;
    const int e  = lin / ((N / 64) * (K / 64));
    unsigned short (*t)[72] = (unsigned short (*)[72])smem;
    const int tid = threadIdx.x;
    const int r  = tid >> 4;
    const int c4 = (tid & 15) * 4;
    const float* src = W + (size_t)e * K * N + (size_t)(k0 + r) * N + nb + c4;
#pragma unroll
    for (int p = 0; p < 4; ++p) {
        const f32x4 v = __builtin_nontemporal_load((const f32x4*)(src + (size_t)p * 16 * N));
        u16x4 o;
        o.x = f2bf(v.x); o.y = f2bf(v.y); o.z = f2bf(v.z); o.w = f2bf(v.w);
        *(u16x4*)(&t[r + p * 16][c4]) = o;
    }
    __syncthreads();
#pragma unroll
    for (int p = 0; p < 4; ++p) {
        const int n  = (tid >> 4) + p * 16;
        const int kk = (tid & 15) * 4;
        u16x4 o;
        o.x = t[kk][n]; o.y = t[kk + 1][n]; o.z = t[kk + 2][n]; o.w = t[kk + 3][n];
        *(u16x4*)(Wb + (size_t)e * N * K + (size_t)(nb + n) * K + k0 + kk) = o;
    }
}

// -------- planner: rowbases, targets, and 8 per-XCD dependency-ordered queues
// nw[2+e] = rowbase[e]; nw[10+e] = G1 target (tiles[e]*32).
// Queue item: type<<28 | payload. type 0=G1 (e<<16|colt<<7|rt),
// 1=tc2 (lin), 2=G2 (e<<16|kc<<13|colt<<7|rt).
// Per-queue order: for e: [tc2(e) share, G1(e) share, G2(e) share] -- every
// item's producers precede it in every queue => head-ordered grabbing can't
// deadlock (spinners imply producers already grabbed/executing).
__global__ void planner_kernel(const int* __restrict__ counts, int* __restrict__ nw,
                               int* __restrict__ queue, int* __restrict__ qlen) {
    __shared__ int tiles[NE];
    const int tid = threadIdx.x;
    if (tid == 0) {
        int rb = 0;
        for (int e = 0; e < NE; ++e) {
            tiles[e] = (counts[e] + 127) >> 7;
            nw[2 + e] = rb;
            rb += counts[e];
            nw[10 + e] = tiles[e] * 32;
        }
    }
    __syncthreads();
    if (tid < 8) {
        const int c = tid;
        int idx = 0;
        int* q = queue + c * Q_STRIDE;
        for (int e = 0; e < NE; ++e) {
            // tc2(e): 1024 items, chunk for this XCD
            {
                const int n = 1024, qd = n >> 3, r = n & 7;
                const int cnt = qd + (c < r ? 1 : 0);
                const int st = c * qd + (c < r ? c : r);
                for (int i = 0; i < cnt; ++i)
                    q[idx++] = (1 << 28) | (e * 1024 + st + i);
            }
            // G1(e): tiles[e]*32 items, order [colt][rt]
            {
                const int n = tiles[e] * 32, qd = n >> 3, r = n & 7;
                const int cnt = qd + (c < r ? 1 : 0);
                const int st = c * qd + (c < r ? c : r);
                for (int i = 0; i < cnt; ++i) {
                    const int gi = st + i;
                    const int colt = gi / tiles[e];
                    const int rt = gi - colt * tiles[e];
                    q[idx++] = (0 << 28) | (e << 16) | (colt << 7) | rt;
                }
            }
            // G2(e): tiles[e]*16 items, order [kc][colt][rt]
            {
                const int n = tiles[e] * 16, qd = n >> 3, r = n & 7;
                const int cnt = qd + (c < r ? 1 : 0);
                const int st = c * qd + (c < r ? c : r);
                for (int i = 0; i < cnt; ++i) {
                    const int gi = st + i;
                    const int kc = gi / (8 * tiles[e]);
                    const int rem = gi - kc * 8 * tiles[e];
                    const int colt = rem / tiles[e];
                    const int rt = rem - colt * tiles[e];
                    q[idx++] = (2 << 28) | (e << 16) | (kc << 13) | (colt << 7) | rt;
                }
            }
        }
        qlen[c] = idx;
    }
}

// ------------- grouped GEMM body, 128x128, BK=64, 4 waves (r7 core) ----------
// PHASE 1: h_compact[rowbase[e]+gr] = gelu(x[rid>>1] @ W1[e] + b1[e])
// PHASE 2: out[rid>>1] += gate * (h_compact[rowbase[e]+gr] @ W2[e] + b2[e])
// LDS [128][64] linear; 3-bit XOR granule swizzle on global source AND
// ds_read side (measured 0 conflicts).  Work item passed directly (w).
template <int PHASE, int SPLITK>
__device__ __forceinline__ void gemm_body(
    const unsigned short* __restrict__ A, const unsigned short* __restrict__ Wb,
    const float* __restrict__ bias, const int* __restrict__ counts,
    const int* __restrict__ rowlist, const float* __restrict__ gatelist,
    const int* __restrict__ nw, unsigned short* __restrict__ h,
    float* __restrict__ out, int w, char* smem) {
    constexpr int K = (PHASE == 1) ? DIM : HID;
    constexpr int N = (PHASE == 1) ? HID : DIM;
    constexpr int KC = K / SPLITK;
    constexpr int NT = KC / 64;
    const int e    = (w >> 16) & 7;
    const int kc   = (w >> 13) & 7;
    const int colt = (w >> 7) & 0x3f;
    const int rt   = w & 0x7f;
    const int cnt  = counts[e];
    const int n0   = colt * 128;
    const int hrow0 = nw[2 + e] + rt * 128;   // compact h row base of this tile

    unsigned short (*As)[64] = (unsigned short (*)[64])smem;            // 16 KB
    unsigned short (*Bs)[64] = (unsigned short (*)[64])(smem + 16384);  // 16 KB
    int*   rows_s  = (int*)(smem + 32768);
    float* gates_s = (float*)(smem + 33280);

    const int tid = threadIdx.x;
    if (tid < 128) {
        const int gr = rt * 128 + tid;
        const int src = e * T_TOKENS + ((gr < cnt) ? gr : 0);
        rows_s[tid] = rowlist[src];
        gates_s[tid] = (gr < cnt) ? gatelist[src] : 0.f;
    }
    __syncthreads();

    const int lane = tid & 63;
    const int wv = tid >> 6;       // 4 waves

    const int rowin = lane >> 3;                      // 0..7
    const int kofs = ((lane & 7) ^ rowin) * 8;        // swizzled source k-elems
    const unsigned short* sA[4];
    const unsigned short* sB[4];
    int dLds[4];
#pragma unroll
    for (int j = 0; j < 4; ++j) {
        const int r = (wv * 4 + j) * 8 + rowin;
        // P1: gather token rows via rowlist; P2: linear compact h rows
        sA[j] = (PHASE == 1)
            ? A + (size_t)(rows_s[r] >> 1) * K + kofs
            : A + (size_t)(hrow0 + r) * K + kc * KC + kofs;
        sB[j] = Wb + (size_t)e * N * K + (size_t)(n0 + r) * K + kc * KC + kofs;
        dLds[j] = (wv * 4 + j) * 8 * 64;              // elements
    }

    const int wr = wv >> 1;   // 2x2 waves, each owns 64x64
    const int wc = wv & 1;
    const int r15 = lane & 15;
    const int hi = lane >> 4;     // 0..3
    const int x7 = lane & 7;

    f32x4 acc[4][4];
#pragma unroll
    for (int m = 0; m < 4; ++m)
#pragma unroll
        for (int n = 0; n < 4; ++n)
#pragma unroll
            for (int r = 0; r < 4; ++r) acc[m][n][r] = 0.f;

    for (int t = 0; t < NT; ++t) {
        const int ko = t * 64;
#pragma unroll
        for (int j = 0; j < 4; ++j) gload16(sA[j] + ko, &As[0][0] + dLds[j]);
#pragma unroll
        for (int j = 0; j < 4; ++j) gload16(sB[j] + ko, &Bs[0][0] + dLds[j]);
        __syncthreads();   // compiler drains vmcnt(0) -> staged data visible

#pragma unroll
        for (int kk = 0; kk < 2; ++kk) {
            const int gsw = ((kk * 4 + hi) ^ x7) * 8;
            short8 af[4], bfr[4];
#pragma unroll
            for (int m = 0; m < 4; ++m)
                af[m] = *(const short8*)(&As[wr * 64 + m * 16 + r15][0] + gsw);
#pragma unroll
            for (int n = 0; n < 4; ++n)
                bfr[n] = *(const short8*)(&Bs[wc * 64 + n * 16 + r15][0] + gsw);
#pragma unroll
            for (int m = 0; m < 4; ++m)
#pragma unroll
                for (int n = 0; n < 4; ++n)
                    acc[m][n] = __builtin_amdgcn_mfma_f32_16x16x32_bf16(af[m], bfr[n], acc[m][n], 0, 0, 0);
        }
        __syncthreads();   // all reads done before next-iter staging overwrites
    }

    // epilogue: C/D layout col=lane&15, row=(lane>>4)*4+r
#pragma unroll
    for (int n = 0; n < 4; ++n) {
        const int col = n0 + wc * 64 + n * 16 + r15;
        const float bv = (PHASE == 1 || kc == 0) ? bias[(size_t)e * N + col] : 0.f;
#pragma unroll
        for (int m = 0; m < 4; ++m) {
            const int rbase = wr * 64 + m * 16 + hi * 4;
#pragma unroll
            for (int r = 0; r < 4; ++r) {
                const int row = rbase + r;
                if (rt * 128 + row < cnt) {
                    if (PHASE == 1) {
                        const float v = acc[m][n][r] + bv;
                        // tanh-approx gelu == v * sigmoid(1.5957691*(v+0.044715 v^3))
                        const float s = 1.f / (1.f + __expf(-1.5957691216f * (v + 0.044715f * v * v * v)));
                        h[(size_t)(hrow0 + row) * HID + col] = f2bf(v * s);  // linear
                    } else {
                        const float v = (acc[m][n][r] + bv) * gates_s[row];
                        atomicAdd(&out[(size_t)(rows_s[row] >> 1) * DIM + col], v);
                    }
                }
            }
        }
    }
}

// ---- K1: prep (blocks 0..1023)  ||  transconv W1 (blocks 1024..9215) --------
__global__ __launch_bounds__(256, 8) void k1_prep_tc1(
    const float* __restrict__ x, const float* __restrict__ Wg,
    const float* __restrict__ bg, int* __restrict__ counts,
    int* __restrict__ rowlist, float* __restrict__ gatelist,
    unsigned short* __restrict__ xb, float* __restrict__ out,
    const float* __restrict__ W1, unsigned short* __restrict__ W1b) {
    __shared__ __align__(16) char smem[TC_SMEM];
    if (blockIdx.x < PREP_BLOCKS)
        prep_body(x, Wg, bg, counts, rowlist, gatelist, xb, out, blockIdx.x);
    else
        transconv_body<DIM, HID>(W1, W1b, blockIdx.x - PREP_BLOCKS, smem);
}

// ---- MEGA: G1 + tc2 + G2 with per-XCD work queues and expert-level gating ---
__global__ __launch_bounds__(256, 4) void k3_mega(
    const unsigned short* __restrict__ xb, const unsigned short* __restrict__ W1b,
    const float* __restrict__ b1, const float* __restrict__ W2,
    unsigned short* __restrict__ W2b, const float* __restrict__ b2,
    unsigned short* __restrict__ h, float* __restrict__ out,
    const int* __restrict__ counts, const int* __restrict__ rowlist,
    const float* __restrict__ gatelist, const int* __restrict__ nw,
    const int* __restrict__ queue, const int* __restrict__ qlen,
    int* __restrict__ qctr, int* __restrict__ g1done, int* __restrict__ tcdone) {
    __shared__ __align__(16) char smem[SMEM_BYTES];
    __shared__ int item_s;
    if (threadIdx.x == 0) {
        int myx;
        asm volatile("s_getreg_b32 %0, hwreg(HW_REG_XCC_ID)" : "=s"(myx));
        myx &= 7;
        int it = -1;
        for (int a = 0; a < 8; ++a) {          // own queue first, then steal
            const int c = (myx + a) & 7;
            const int qi = atomicAdd(&qctr[c], 1);
            if (qi < qlen[c]) { it = queue[c * Q_STRIDE + qi]; break; }
        }
        item_s = it;
    }
    __syncthreads();
    const int it = item_s;
    if (it == -1) return;
    const int type = (it >> 28) & 3;
    if (type == 1) {
        const int lin = it & 0x3fff;
        transconv_body<HID, DIM>(W2, W2b, lin, smem);
        __syncthreads();
        if (threadIdx.x == 0) {
            __threadfence();                   // release: W2b visible device-wide
            atomicAdd(&tcdone[lin >> 10], 1);
        }
    } else if (type == 0) {
        gemm_body<1, 1>(xb, W1b, b1, counts, rowlist, gatelist, nw,
                        h, nullptr, it & 0xfffffff, smem);
        __syncthreads();
        if (threadIdx.x == 0) {
            __threadfence();                   // release: h visible device-wide
            atomicAdd(&g1done[(it >> 16) & 7], 1);
        }
    } else {
        const int e = (it >> 16) & 7;
        if (threadIdx.x == 0) {
            const int tgt1 = nw[10 + e];
            while (__hip_atomic_load(&g1done[e], __ATOMIC_RELAXED, __HIP_MEMORY_SCOPE_AGENT) < tgt1 ||
                   __hip_atomic_load(&tcdone[e], __ATOMIC_RELAXED, __HIP_MEMORY_SCOPE_AGENT) < 1024)
                __builtin_amdgcn_s_sleep(8);
        }
        __syncthreads();
        __threadfence();                       // acquire: invalidate stale h/W2b
        __syncthreads();
        gemm_body<2, 2>(h, W2b, b2, counts, rowlist, gatelist, nw,
                        nullptr, out, it & 0xfffffff, smem);
    }
}

extern "C" void kernel_launch(void* const* d_in, const int* in_sizes, int n_in,
                              void* d_out, int out_size, void* d_ws, size_t ws_size,
                              hipStream_t stream) {
    (void)in_sizes; (void)n_in; (void)out_size; (void)ws_size;
    const float* x  = (const float*)d_in[0];
    const float* Wg = (const float*)d_in[1];
    const float* bg = (const float*)d_in[2];
    const float* W1 = (const float*)d_in[3];
    const float* b1 = (const float*)d_in[4];
    const float* W2 = (const float*)d_in[5];
    const float* b2 = (const float*)d_in[6];
    float* out = (float*)d_out;

    char* ws = (char*)d_ws;
    size_t off = 0;
    auto alloc = [&](size_t bytes) -> void* {
        size_t a = (off + 255) & ~(size_t)255;
        off = a + bytes;
        return (void*)(ws + a);
    };
    int*   counts   = (int*)alloc(NE * sizeof(int));
    int*   flags    = (int*)alloc(24 * sizeof(int));   // qctr[8], g1done[8], tcdone[8]
    int*   nw       = (int*)alloc(18 * sizeof(int));
    int*   queue    = (int*)alloc(8 * Q_STRIDE * sizeof(int));
    int*   qlen     = (int*)alloc(8 * sizeof(int));
    int*   rowlist  = (int*)alloc((size_t)NE * T_TOKENS * sizeof(int));
    float* gatelist = (float*)alloc((size_t)NE * T_TOKENS * sizeof(float));
    unsigned short* xb  = (unsigned short*)alloc((size_t)T_TOKENS * DIM * 2);
    unsigned short* h   = (unsigned short*)alloc((size_t)T_TOKENS * TOPK * HID * 2);
    unsigned short* W1b = (unsigned short*)alloc((size_t)NE * DIM * HID * 2);
    unsigned short* W2b = (unsigned short*)alloc((size_t)NE * HID * DIM * 2);
    // total ws use: ~200.5 MB

    int* qctr   = flags;
    int* g1done = flags + 8;
    int* tcdone = flags + 16;

    hipMemsetAsync(counts, 0, NE * sizeof(int), stream);
    hipMemsetAsync(flags, 0, 24 * sizeof(int), stream);
    // K1: prep || transconv W1   (9 KB LDS -> 8 blocks/CU)
    k1_prep_tc1<<<PREP_BLOCKS + TC_BLOCKS, 256, 0, stream>>>(
        x, Wg, bg, counts, rowlist, gatelist, xb, out, W1, W1b);
    planner_kernel<<<1, 64, 0, stream>>>(counts, nw, queue, qlen);
    // MEGA: G1 + tc2 + G2, dependency-ordered per-XCD queues
    k3_mega<<<MEGA_BLOCKS, 256, 0, stream>>>(
        xb, W1b, b1, W2, W2b, b2, h, out, counts, rowlist, gatelist, nw,
        queue, qlen, qctr, g1done, tcdone);
}

// Round 17
// 402.857 us; speedup vs baseline: 6.1156x; 6.1156x over previous
//
#include <hip/hip_runtime.h>

#define T_TOKENS 4096
#define DIM      1024
#define HID      4096
#define NE       8
#define TOPK     2
#define MAXT128  72   // sum_e ceil(cnt_e/128) <= 8192/128 + 7 = 71

#define PREP_BLOCKS (T_TOKENS / 4)                  // 1024
#define TC_BLOCKS   (NE * (DIM / 64) * (HID / 64))  // 8192 (both directions)
#define G1_BLOCKS   (MAXT128 * 32)                  // 2304
#define G2_BLOCKS   (MAXT128 * 16)                  // 1152
#define SMEM_BYTES  33792                           // GEMM: 16K+16K+512+512
#define TC_SMEM     9216                            // 64x72x2 transconv tile

typedef __attribute__((ext_vector_type(8))) short short8;
typedef __attribute__((ext_vector_type(4))) float f32x4;
typedef __attribute__((ext_vector_type(4))) unsigned short u16x4;

__device__ __forceinline__ unsigned short f2bf(float f) {
    unsigned int u = __builtin_bit_cast(unsigned int, f);
    u += 0x7fffu + ((u >> 16) & 1u);
    return (unsigned short)(u >> 16);
}

__device__ __forceinline__ void gload16(const void* g, void* l) {
    __builtin_amdgcn_global_load_lds(
        (const __attribute__((address_space(1))) unsigned int*)g,
        (__attribute__((address_space(3))) unsigned int*)l, 16, 0, 0);
}

// ------- prep body: router (top2 softmax gate scatter) + x->bf16 + out=x -----
__device__ __forceinline__ void prep_body(
    const float* __restrict__ x, const float* __restrict__ Wg,
    const float* __restrict__ bg, int* __restrict__ counts,
    int* __restrict__ rowlist, float* __restrict__ gatelist,
    unsigned short* __restrict__ xb, float* __restrict__ out, int bid) {
    const int wid  = threadIdx.x >> 6;
    const int lane = threadIdx.x & 63;
    const int t = bid * 4 + wid;
    float acc[NE];
#pragma unroll
    for (int e = 0; e < NE; ++e) acc[e] = 0.f;
    const float* xr = x + (size_t)t * DIM;
    for (int d = lane; d < DIM; d += 64) {
        const float xv = xr[d];
        const float* wr = Wg + (size_t)d * NE;
#pragma unroll
        for (int e = 0; e < NE; ++e) acc[e] += xv * wr[e];
    }
#pragma unroll
    for (int off = 32; off > 0; off >>= 1) {
#pragma unroll
        for (int e = 0; e < NE; ++e) acc[e] += __shfl_xor(acc[e], off);
    }
    if (lane == 0) {
        float lg[NE];
#pragma unroll
        for (int e = 0; e < NE; ++e) lg[e] = acc[e] + bg[e];
        int i1 = 0; float v1 = lg[0];
#pragma unroll
        for (int e = 1; e < NE; ++e) if (lg[e] > v1) { v1 = lg[e]; i1 = e; }
        int i2 = -1; float v2 = -3.4e38f;
#pragma unroll
        for (int e = 0; e < NE; ++e) if (e != i1 && lg[e] > v2) { v2 = lg[e]; i2 = e; }
        const float ex = expf(v2 - v1);            // v1 >= v2
        const float g1 = 1.f / (1.f + ex);
        const float g2 = ex / (1.f + ex);
        int p1 = atomicAdd(&counts[i1], 1);
        rowlist[i1 * T_TOKENS + p1] = t * 2;
        gatelist[i1 * T_TOKENS + p1] = g1;
        int p2 = atomicAdd(&counts[i2], 1);
        rowlist[i2 * T_TOKENS + p2] = t * 2 + 1;
        gatelist[i2 * T_TOKENS + p2] = g2;
    }
    const float4* xr4 = (const float4*)xr;
    float4* o4 = (float4*)(out + (size_t)t * DIM);
    ushort4* xb4 = (ushort4*)(xb + (size_t)t * DIM);
#pragma unroll
    for (int p = 0; p < 4; ++p) {
        const int i = p * 64 + lane;
        const float4 v = xr4[i];
        o4[i] = v;
        ushort4 o;
        o.x = f2bf(v.x); o.y = f2bf(v.y); o.z = f2bf(v.z); o.w = f2bf(v.w);
        xb4[i] = o;
    }
}

// --- transconv body: W [e][K][N] f32 -> Wb [e][N][K] bf16, nontemporal reads -
template <int K, int N>
__device__ __forceinline__ void transconv_body(const float* __restrict__ W,
                                               unsigned short* __restrict__ Wb,
                                               int lin, char* smem) {
    const int nb = (lin % (N / 64)) * 64;
    const int k0 = ((lin / (N / 64)) % (K / 64)) * 64;
    const int e  = lin / ((N / 64) * (K / 64));
    unsigned short (*t)[72] = (unsigned short (*)[72])smem;
    const int tid = threadIdx.x;
    const int r  = tid >> 4;
    const int c4 = (tid & 15) * 4;
    const float* src = W + (size_t)e * K * N + (size_t)(k0 + r) * N + nb + c4;
#pragma unroll
    for (int p = 0; p < 4; ++p) {
        const f32x4 v = __builtin_nontemporal_load((const f32x4*)(src + (size_t)p * 16 * N));
        u16x4 o;
        o.x = f2bf(v.x); o.y = f2bf(v.y); o.z = f2bf(v.z); o.w = f2bf(v.w);
        *(u16x4*)(&t[r + p * 16][c4]) = o;
    }
    __syncthreads();
#pragma unroll
    for (int p = 0; p < 4; ++p) {
        const int n  = (tid >> 4) + p * 16;
        const int kk = (tid & 15) * 4;
        u16x4 o;
        o.x = t[kk][n]; o.y = t[kk + 1][n]; o.z = t[kk + 2][n]; o.w = t[kk + 3][n];
        *(u16x4*)(Wb + (size_t)e * N * K + (size_t)(nb + n) * K + k0 + kk) = o;
    }
}

// -------- planner: worklists + per-expert compact row bases ------------------
// wl1: [e][colt][rt].  wl2: supertiled [e][kc][rtg4][colt][rti].
// nw[0]/nw[1] = work counts; nw[2+e] = rowbase[e] (exclusive prefix of counts)
// for the expert-compacted h layout (h row = rowbase[e] + rt*128 + i).
__global__ void planner_kernel(const int* __restrict__ counts, int* __restrict__ wl1,
                               int* __restrict__ wl2, int* __restrict__ nw) {
    __shared__ int tiles[NE], pref[NE + 1];
    const int tid = threadIdx.x;
    if (tid == 0) {
        int p = 0, rb = 0;
        for (int e = 0; e < NE; ++e) {
            tiles[e] = (counts[e] + 127) >> 7;
            pref[e] = p;
            p += tiles[e];
            nw[2 + e] = rb;
            rb += counts[e];
        }
        pref[NE] = p;
        nw[0] = p * 32;      // phase 1: 32 col-panels, splitk 1
        nw[1] = p * 16;      // phase 2: 8 col-panels, splitk 2
    }
    __syncthreads();
    const int n1 = pref[NE] * 32;
    for (int i = tid; i < n1; i += 256) {
        int e = 0;
        while (pref[e + 1] * 32 <= i) ++e;
        const int rel = i - pref[e] * 32;
        const int colt = rel / tiles[e];
        const int rt = rel - colt * tiles[e];
        wl1[i] = (e << 16) | (colt << 7) | rt;
    }
    // wl2: one thread per expert builds its supertiled range sequentially.
    if (tid < NE) {
        const int e = tid;
        const int te = tiles[e];
        int idx = pref[e] * 16;
        for (int kc = 0; kc < 2; ++kc)
            for (int rt0 = 0; rt0 < te; rt0 += 4) {
                const int rt1 = (rt0 + 4 < te) ? (rt0 + 4) : te;
                for (int colt = 0; colt < 8; ++colt)
                    for (int rt = rt0; rt < rt1; ++rt)
                        wl2[idx++] = (e << 16) | (kc << 13) | (colt << 7) | rt;
            }
    }
}

// ------------- grouped GEMM body, 128x128, BK=64, 4 waves (r7 core) ----------
// PHASE 1: h_compact[rowbase[e]+gr] = gelu(x[rid>>1] @ W1[e] + b1[e]),
//          C-tile staged through LDS -> fully coalesced 128B h-writes (r17).
// PHASE 2: out[rid>>1] += gate * (h_compact[rowbase[e]+gr] @ W2[e] + b2[e])
// XCD-chunked worklist; LDS [128][64] linear; 3-bit XOR granule swizzle on
// global source AND ds_read side (measured 0 conflicts).
template <int PHASE, int SPLITK>
__device__ __forceinline__ void gemm_body(
    const unsigned short* __restrict__ A, const unsigned short* __restrict__ Wb,
    const float* __restrict__ bias, const int* __restrict__ counts,
    const int* __restrict__ rowlist, const float* __restrict__ gatelist,
    const int* __restrict__ wl, const int* __restrict__ nw,
    unsigned short* __restrict__ h, float* __restrict__ out,
    int bid, char* smem) {
    constexpr int K = (PHASE == 1) ? DIM : HID;
    constexpr int N = (PHASE == 1) ? HID : DIM;
    constexpr int KC = K / SPLITK;
    constexpr int NT = KC / 64;
    const int nwork = nw[PHASE - 1];
    const int chunk = (nwork + 7) >> 3;
    const int pos = bid >> 3;
    if (pos >= chunk) return;
    const int widx = (bid & 7) * chunk + pos;
    if (widx >= nwork) return;
    const int w = wl[widx];
    const int e    = (w >> 16) & 7;
    const int kc   = (w >> 13) & 7;
    const int colt = (w >> 7) & 0x3f;
    const int rt   = w & 0x7f;
    const int cnt  = counts[e];
    const int n0   = colt * 128;
    const int hrow0 = nw[2 + e] + rt * 128;   // compact h row base of this tile

    unsigned short (*As)[64] = (unsigned short (*)[64])smem;            // 16 KB
    unsigned short (*Bs)[64] = (unsigned short (*)[64])(smem + 16384);  // 16 KB
    int*   rows_s  = (int*)(smem + 32768);
    float* gates_s = (float*)(smem + 33280);

    const int tid = threadIdx.x;
    if (tid < 128) {
        const int gr = rt * 128 + tid;
        const int src = e * T_TOKENS + ((gr < cnt) ? gr : 0);
        rows_s[tid] = rowlist[src];
        gates_s[tid] = (gr < cnt) ? gatelist[src] : 0.f;
    }
    __syncthreads();

    const int lane = tid & 63;
    const int wv = tid >> 6;       // 4 waves

    const int rowin = lane >> 3;                      // 0..7
    const int kofs = ((lane & 7) ^ rowin) * 8;        // swizzled source k-elems
    const unsigned short* sA[4];
    const unsigned short* sB[4];
    int dLds[4];
#pragma unroll
    for (int j = 0; j < 4; ++j) {
        const int r = (wv * 4 + j) * 8 + rowin;
        // P1: gather token rows via rowlist; P2: linear compact h rows
        sA[j] = (PHASE == 1)
            ? A + (size_t)(rows_s[r] >> 1) * K + kofs
            : A + (size_t)(hrow0 + r) * K + kc * KC + kofs;
        sB[j] = Wb + (size_t)e * N * K + (size_t)(n0 + r) * K + kc * KC + kofs;
        dLds[j] = (wv * 4 + j) * 8 * 64;              // elements
    }

    const int wr = wv >> 1;   // 2x2 waves, each owns 64x64
    const int wc = wv & 1;
    const int r15 = lane & 15;
    const int hi = lane >> 4;     // 0..3
    const int x7 = lane & 7;

    f32x4 acc[4][4];
#pragma unroll
    for (int m = 0; m < 4; ++m)
#pragma unroll
        for (int n = 0; n < 4; ++n)
#pragma unroll
            for (int r = 0; r < 4; ++r) acc[m][n][r] = 0.f;

    for (int t = 0; t < NT; ++t) {
        const int ko = t * 64;
#pragma unroll
        for (int j = 0; j < 4; ++j) gload16(sA[j] + ko, &As[0][0] + dLds[j]);
#pragma unroll
        for (int j = 0; j < 4; ++j) gload16(sB[j] + ko, &Bs[0][0] + dLds[j]);
        __syncthreads();   // compiler drains vmcnt(0) -> staged data visible

#pragma unroll
        for (int kk = 0; kk < 2; ++kk) {
            const int gsw = ((kk * 4 + hi) ^ x7) * 8;
            short8 af[4], bfr[4];
#pragma unroll
            for (int m = 0; m < 4; ++m)
                af[m] = *(const short8*)(&As[wr * 64 + m * 16 + r15][0] + gsw);
#pragma unroll
            for (int n = 0; n < 4; ++n)
                bfr[n] = *(const short8*)(&Bs[wc * 64 + n * 16 + r15][0] + gsw);
#pragma unroll
            for (int m = 0; m < 4; ++m)
#pragma unroll
                for (int n = 0; n < 4; ++n)
                    acc[m][n] = __builtin_amdgcn_mfma_f32_16x16x32_bf16(af[m], bfr[n], acc[m][n], 0, 0, 0);
        }
        __syncthreads();   // all reads done before next-iter staging overwrites
    }

    // epilogue: C/D layout col=lane&15, row=(lane>>4)*4+r
    if (PHASE == 1) {
        // stage C-tile (128x128 bf16 = 32 KB) in LDS over dead As/Bs, then
        // write h in coalesced 128B-per-thread bursts (fix 32B-scatter ampl.)
        unsigned short (*Cs)[128] = (unsigned short (*)[128])smem;
#pragma unroll
        for (int n = 0; n < 4; ++n) {
            const int col = wc * 64 + n * 16 + r15;
            const float bv = bias[(size_t)e * N + n0 + col];
#pragma unroll
            for (int m = 0; m < 4; ++m) {
#pragma unroll
                for (int r = 0; r < 4; ++r) {
                    const int row = wr * 64 + m * 16 + hi * 4 + r;
                    const float v = acc[m][n][r] + bv;
                    // tanh-approx gelu == v * sigmoid(1.5957691*(v+0.044715 v^3))
                    const float s = 1.f / (1.f + __expf(-1.5957691216f * (v + 0.044715f * v * v * v)));
                    Cs[row][col] = f2bf(v * s);
                }
            }
        }
        __syncthreads();
        const int row = tid >> 1;
        if (rt * 128 + row < cnt) {     // don't spill into next expert's rows
            const uint4* srcv = (const uint4*)&Cs[row][(tid & 1) * 64];
            uint4* dstv = (uint4*)(h + (size_t)(hrow0 + row) * HID + n0 + (tid & 1) * 64);
#pragma unroll
            for (int p = 0; p < 8; ++p) dstv[p] = srcv[p];
        }
    } else {
#pragma unroll
        for (int n = 0; n < 4; ++n) {
            const int col = n0 + wc * 64 + n * 16 + r15;
            const float bv = (kc == 0) ? bias[(size_t)e * N + col] : 0.f;
#pragma unroll
            for (int m = 0; m < 4; ++m) {
                const int rbase = wr * 64 + m * 16 + hi * 4;
#pragma unroll
                for (int r = 0; r < 4; ++r) {
                    const int row = rbase + r;
                    if (rt * 128 + row < cnt) {
                        const float v = (acc[m][n][r] + bv) * gates_s[row];
                        atomicAdd(&out[(size_t)(rows_s[row] >> 1) * DIM + col], v);
                    }
                }
            }
        }
    }
}

// ---- K1: prep (blocks 0..1023)  ||  transconv W1 (blocks 1024..9215) --------
// Own 9 KB LDS (NOT the 33 KB GEMM union) -> 8 blocks/CU for latency hiding.
__global__ __launch_bounds__(256, 8) void k1_prep_tc1(
    const float* __restrict__ x, const float* __restrict__ Wg,
    const float* __restrict__ bg, int* __restrict__ counts,
    int* __restrict__ rowlist, float* __restrict__ gatelist,
    unsigned short* __restrict__ xb, float* __restrict__ out,
    const float* __restrict__ W1, unsigned short* __restrict__ W1b) {
    __shared__ __align__(16) char smem[TC_SMEM];
    if (blockIdx.x < PREP_BLOCKS)
        prep_body(x, Wg, bg, counts, rowlist, gatelist, xb, out, blockIdx.x);
    else
        transconv_body<DIM, HID>(W1, W1b, blockIdx.x - PREP_BLOCKS, smem);
}

// ---- K3: GEMM1 (blocks 0..2303)  ||  transconv W2 (blocks 2304..10495) ------
__global__ __launch_bounds__(256, 4) void k3_gemm1_tc2(
    const unsigned short* __restrict__ xb, const unsigned short* __restrict__ W1b,
    const float* __restrict__ b1, const int* __restrict__ counts,
    const int* __restrict__ rowlist, const float* __restrict__ gatelist,
    const int* __restrict__ wl1, const int* __restrict__ nw,
    unsigned short* __restrict__ h,
    const float* __restrict__ W2, unsigned short* __restrict__ W2b) {
    __shared__ __align__(16) char smem[SMEM_BYTES];
    if (blockIdx.x < G1_BLOCKS)
        gemm_body<1, 1>(xb, W1b, b1, counts, rowlist, gatelist, wl1, nw,
                        h, nullptr, blockIdx.x, smem);
    else
        transconv_body<HID, DIM>(W2, W2b, blockIdx.x - G1_BLOCKS, smem);
}

// ---- K4: GEMM2 ---------------------------------------------------------------
__global__ __launch_bounds__(256, 4) void k4_gemm2(
    const unsigned short* __restrict__ h, const unsigned short* __restrict__ W2b,
    const float* __restrict__ b2, const int* __restrict__ counts,
    const int* __restrict__ rowlist, const float* __restrict__ gatelist,
    const int* __restrict__ wl2, const int* __restrict__ nw,
    float* __restrict__ out) {
    __shared__ __align__(16) char smem[SMEM_BYTES];
    gemm_body<2, 2>(h, W2b, b2, counts, rowlist, gatelist, wl2, nw,
                    nullptr, out, blockIdx.x, smem);
}

extern "C" void kernel_launch(void* const* d_in, const int* in_sizes, int n_in,
                              void* d_out, int out_size, void* d_ws, size_t ws_size,
                              hipStream_t stream) {
    (void)in_sizes; (void)n_in; (void)out_size; (void)ws_size;
    const float* x  = (const float*)d_in[0];
    const float* Wg = (const float*)d_in[1];
    const float* bg = (const float*)d_in[2];
    const float* W1 = (const float*)d_in[3];
    const float* b1 = (const float*)d_in[4];
    const float* W2 = (const float*)d_in[5];
    const float* b2 = (const float*)d_in[6];
    float* out = (float*)d_out;

    char* ws = (char*)d_ws;
    size_t off = 0;
    auto alloc = [&](size_t bytes) -> void* {
        size_t a = (off + 255) & ~(size_t)255;
        off = a + bytes;
        return (void*)(ws + a);
    };
    int*   counts   = (int*)alloc(NE * sizeof(int));
    int*   nw       = (int*)alloc((2 + NE) * sizeof(int));
    int*   wl1      = (int*)alloc((size_t)MAXT128 * 32 * sizeof(int));
    int*   wl2      = (int*)alloc((size_t)MAXT128 * 16 * sizeof(int));
    int*   rowlist  = (int*)alloc((size_t)NE * T_TOKENS * sizeof(int));
    float* gatelist = (float*)alloc((size_t)NE * T_TOKENS * sizeof(float));
    unsigned short* xb  = (unsigned short*)alloc((size_t)T_TOKENS * DIM * 2);
    unsigned short* h   = (unsigned short*)alloc((size_t)T_TOKENS * TOPK * HID * 2);
    unsigned short* W1b = (unsigned short*)alloc((size_t)NE * DIM * HID * 2);
    unsigned short* W2b = (unsigned short*)alloc((size_t)NE * HID * DIM * 2);
    // total ws use: ~200.4 MB

    hipMemsetAsync(counts, 0, NE * sizeof(int), stream);
    // K1: prep || transconv W1   (9 KB LDS -> 8 blocks/CU)
    k1_prep_tc1<<<PREP_BLOCKS + TC_BLOCKS, 256, 0, stream>>>(
        x, Wg, bg, counts, rowlist, gatelist, xb, out, W1, W1b);
    planner_kernel<<<1, 256, 0, stream>>>(counts, wl1, wl2, nw);
    // K3: GEMM1 || transconv W2  (GEMM1 needs only W1b; tc2 fills stall slots)
    k3_gemm1_tc2<<<G1_BLOCKS + TC_BLOCKS, 256, 0, stream>>>(
        xb, W1b, b1, counts, rowlist, gatelist, wl1, nw, h, W2, W2b);
    // K4: GEMM2 on expert-compacted h (linear A-reads)
    k4_gemm2<<<G2_BLOCKS, 256, 0, stream>>>(
        h, W2b, b2, counts, rowlist, gatelist, wl2, nw, out);
}

// Round 18
// 400.885 us; speedup vs baseline: 6.1457x; 1.0049x over previous
//
#include <hip/hip_runtime.h>

#define T_TOKENS 4096
#define DIM      1024
#define HID      4096
#define NE       8
#define TOPK     2
#define MAXT128  72   // sum_e ceil(cnt_e/128) <= 8192/128 + 7 = 71

#define PREP_BLOCKS (T_TOKENS / 4)                  // 1024
#define TC_BLOCKS   (NE * (DIM / 64) * (HID / 64))  // 8192 (both directions)
#define G1_BLOCKS   (MAXT128 * 32)                  // 2304
#define G2_BLOCKS   (MAXT128 * 16)                  // 1152
#define SMEM_BYTES  33792                           // GEMM: 16K+16K+512+512
#define TC_SMEM     9216                            // 64x72x2 transconv tile

typedef __attribute__((ext_vector_type(8))) short short8;
typedef __attribute__((ext_vector_type(4))) float f32x4;
typedef __attribute__((ext_vector_type(4))) unsigned short u16x4;

__device__ __forceinline__ unsigned short f2bf(float f) {
    unsigned int u = __builtin_bit_cast(unsigned int, f);
    u += 0x7fffu + ((u >> 16) & 1u);
    return (unsigned short)(u >> 16);
}

__device__ __forceinline__ void gload16(const void* g, void* l) {
    __builtin_amdgcn_global_load_lds(
        (const __attribute__((address_space(1))) unsigned int*)g,
        (__attribute__((address_space(3))) unsigned int*)l, 16, 0, 0);
}

// ------- prep body: router (top2 softmax gate scatter) + x->bf16 + out=x -----
__device__ __forceinline__ void prep_body(
    const float* __restrict__ x, const float* __restrict__ Wg,
    const float* __restrict__ bg, int* __restrict__ counts,
    int* __restrict__ rowlist, float* __restrict__ gatelist,
    unsigned short* __restrict__ xb, float* __restrict__ out, int bid) {
    const int wid  = threadIdx.x >> 6;
    const int lane = threadIdx.x & 63;
    const int t = bid * 4 + wid;
    float acc[NE];
#pragma unroll
    for (int e = 0; e < NE; ++e) acc[e] = 0.f;
    const float* xr = x + (size_t)t * DIM;
    for (int d = lane; d < DIM; d += 64) {
        const float xv = xr[d];
        const float* wr = Wg + (size_t)d * NE;
#pragma unroll
        for (int e = 0; e < NE; ++e) acc[e] += xv * wr[e];
    }
#pragma unroll
    for (int off = 32; off > 0; off >>= 1) {
#pragma unroll
        for (int e = 0; e < NE; ++e) acc[e] += __shfl_xor(acc[e], off);
    }
    if (lane == 0) {
        float lg[NE];
#pragma unroll
        for (int e = 0; e < NE; ++e) lg[e] = acc[e] + bg[e];
        int i1 = 0; float v1 = lg[0];
#pragma unroll
        for (int e = 1; e < NE; ++e) if (lg[e] > v1) { v1 = lg[e]; i1 = e; }
        int i2 = -1; float v2 = -3.4e38f;
#pragma unroll
        for (int e = 0; e < NE; ++e) if (e != i1 && lg[e] > v2) { v2 = lg[e]; i2 = e; }
        const float ex = expf(v2 - v1);            // v1 >= v2
        const float g1 = 1.f / (1.f + ex);
        const float g2 = ex / (1.f + ex);
        int p1 = atomicAdd(&counts[i1], 1);
        rowlist[i1 * T_TOKENS + p1] = t * 2;
        gatelist[i1 * T_TOKENS + p1] = g1;
        int p2 = atomicAdd(&counts[i2], 1);
        rowlist[i2 * T_TOKENS + p2] = t * 2 + 1;
        gatelist[i2 * T_TOKENS + p2] = g2;
    }
    const float4* xr4 = (const float4*)xr;
    float4* o4 = (float4*)(out + (size_t)t * DIM);
    ushort4* xb4 = (ushort4*)(xb + (size_t)t * DIM);
#pragma unroll
    for (int p = 0; p < 4; ++p) {
        const int i = p * 64 + lane;
        const float4 v = xr4[i];
        o4[i] = v;
        ushort4 o;
        o.x = f2bf(v.x); o.y = f2bf(v.y); o.z = f2bf(v.z); o.w = f2bf(v.w);
        xb4[i] = o;
    }
}

// --- transconv body: W [e][K][N] f32 -> Wb [e][N][K] bf16, nontemporal reads -
template <int K, int N>
__device__ __forceinline__ void transconv_body(const float* __restrict__ W,
                                               unsigned short* __restrict__ Wb,
                                               int lin, char* smem) {
    const int nb = (lin % (N / 64)) * 64;
    const int k0 = ((lin / (N / 64)) % (K / 64)) * 64;
    const int e  = lin / ((N / 64) * (K / 64));
    unsigned short (*t)[72] = (unsigned short (*)[72])smem;
    const int tid = threadIdx.x;
    const int r  = tid >> 4;
    const int c4 = (tid & 15) * 4;
    const float* src = W + (size_t)e * K * N + (size_t)(k0 + r) * N + nb + c4;
#pragma unroll
    for (int p = 0; p < 4; ++p) {
        const f32x4 v = __builtin_nontemporal_load((const f32x4*)(src + (size_t)p * 16 * N));
        u16x4 o;
        o.x = f2bf(v.x); o.y = f2bf(v.y); o.z = f2bf(v.z); o.w = f2bf(v.w);
        *(u16x4*)(&t[r + p * 16][c4]) = o;
    }
    __syncthreads();
#pragma unroll
    for (int p = 0; p < 4; ++p) {
        const int n  = (tid >> 4) + p * 16;
        const int kk = (tid & 15) * 4;
        u16x4 o;
        o.x = t[kk][n]; o.y = t[kk + 1][n]; o.z = t[kk + 2][n]; o.w = t[kk + 3][n];
        *(u16x4*)(Wb + (size_t)e * N * K + (size_t)(nb + n) * K + k0 + kk) = o;
    }
}

// -------- planner: worklists + per-expert compact row bases ------------------
// wl1: [e][colt][rt].  wl2: supertiled [e][kc][rtg4][colt][rti].
// nw[0]/nw[1] = work counts; nw[2+e] = rowbase[e] (exclusive prefix of counts)
// for the expert-compacted h layout (h row = rowbase[e] + rt*128 + i).
__global__ void planner_kernel(const int* __restrict__ counts, int* __restrict__ wl1,
                               int* __restrict__ wl2, int* __restrict__ nw) {
    __shared__ int tiles[NE], pref[NE + 1];
    const int tid = threadIdx.x;
    if (tid == 0) {
        int p = 0, rb = 0;
        for (int e = 0; e < NE; ++e) {
            tiles[e] = (counts[e] + 127) >> 7;
            pref[e] = p;
            p += tiles[e];
            nw[2 + e] = rb;
            rb += counts[e];
        }
        pref[NE] = p;
        nw[0] = p * 32;      // phase 1: 32 col-panels, splitk 1
        nw[1] = p * 16;      // phase 2: 8 col-panels, splitk 2
    }
    __syncthreads();
    const int n1 = pref[NE] * 32;
    for (int i = tid; i < n1; i += 256) {
        int e = 0;
        while (pref[e + 1] * 32 <= i) ++e;
        const int rel = i - pref[e] * 32;
        const int colt = rel / tiles[e];
        const int rt = rel - colt * tiles[e];
        wl1[i] = (e << 16) | (colt << 7) | rt;
    }
    // wl2: one thread per expert builds its supertiled range sequentially.
    if (tid < NE) {
        const int e = tid;
        const int te = tiles[e];
        int idx = pref[e] * 16;
        for (int kc = 0; kc < 2; ++kc)
            for (int rt0 = 0; rt0 < te; rt0 += 4) {
                const int rt1 = (rt0 + 4 < te) ? (rt0 + 4) : te;
                for (int colt = 0; colt < 8; ++colt)
                    for (int rt = rt0; rt < rt1; ++rt)
                        wl2[idx++] = (e << 16) | (kc << 13) | (colt << 7) | rt;
            }
    }
}

// ------------- grouped GEMM body, 128x128, BK=64, 4 waves (r7 core) ----------
// PHASE 1: h_compact[rowbase[e]+gr] = gelu(x[rid>>1] @ W1[e] + b1[e]),
//          C-tile staged through LDS -> fully coalesced 128B h-writes (r17).
// PHASE 2: out[rid>>1] += gate * (h_compact[rowbase[e]+gr] @ W2[e] + b2[e])
// r18: setprio(1) around the MFMA cluster (T5) -- K3 has wave role-diversity
// (GEMM blocks co-resident with tc2 streaming blocks), the T5 prerequisite.
// XCD-chunked worklist; LDS [128][64] linear; 3-bit XOR granule swizzle on
// global source AND ds_read side (measured 0 conflicts).
template <int PHASE, int SPLITK>
__device__ __forceinline__ void gemm_body(
    const unsigned short* __restrict__ A, const unsigned short* __restrict__ Wb,
    const float* __restrict__ bias, const int* __restrict__ counts,
    const int* __restrict__ rowlist, const float* __restrict__ gatelist,
    const int* __restrict__ wl, const int* __restrict__ nw,
    unsigned short* __restrict__ h, float* __restrict__ out,
    int bid, char* smem) {
    constexpr int K = (PHASE == 1) ? DIM : HID;
    constexpr int N = (PHASE == 1) ? HID : DIM;
    constexpr int KC = K / SPLITK;
    constexpr int NT = KC / 64;
    const int nwork = nw[PHASE - 1];
    const int chunk = (nwork + 7) >> 3;
    const int pos = bid >> 3;
    if (pos >= chunk) return;
    const int widx = (bid & 7) * chunk + pos;
    if (widx >= nwork) return;
    const int w = wl[widx];
    const int e    = (w >> 16) & 7;
    const int kc   = (w >> 13) & 7;
    const int colt = (w >> 7) & 0x3f;
    const int rt   = w & 0x7f;
    const int cnt  = counts[e];
    const int n0   = colt * 128;
    const int hrow0 = nw[2 + e] + rt * 128;   // compact h row base of this tile

    unsigned short (*As)[64] = (unsigned short (*)[64])smem;            // 16 KB
    unsigned short (*Bs)[64] = (unsigned short (*)[64])(smem + 16384);  // 16 KB
    int*   rows_s  = (int*)(smem + 32768);
    float* gates_s = (float*)(smem + 33280);

    const int tid = threadIdx.x;
    if (tid < 128) {
        const int gr = rt * 128 + tid;
        const int src = e * T_TOKENS + ((gr < cnt) ? gr : 0);
        rows_s[tid] = rowlist[src];
        gates_s[tid] = (gr < cnt) ? gatelist[src] : 0.f;
    }
    __syncthreads();

    const int lane = tid & 63;
    const int wv = tid >> 6;       // 4 waves

    const int rowin = lane >> 3;                      // 0..7
    const int kofs = ((lane & 7) ^ rowin) * 8;        // swizzled source k-elems
    const unsigned short* sA[4];
    const unsigned short* sB[4];
    int dLds[4];
#pragma unroll
    for (int j = 0; j < 4; ++j) {
        const int r = (wv * 4 + j) * 8 + rowin;
        // P1: gather token rows via rowlist; P2: linear compact h rows
        sA[j] = (PHASE == 1)
            ? A + (size_t)(rows_s[r] >> 1) * K + kofs
            : A + (size_t)(hrow0 + r) * K + kc * KC + kofs;
        sB[j] = Wb + (size_t)e * N * K + (size_t)(n0 + r) * K + kc * KC + kofs;
        dLds[j] = (wv * 4 + j) * 8 * 64;              // elements
    }

    const int wr = wv >> 1;   // 2x2 waves, each owns 64x64
    const int wc = wv & 1;
    const int r15 = lane & 15;
    const int hi = lane >> 4;     // 0..3
    const int x7 = lane & 7;

    f32x4 acc[4][4];
#pragma unroll
    for (int m = 0; m < 4; ++m)
#pragma unroll
        for (int n = 0; n < 4; ++n)
#pragma unroll
            for (int r = 0; r < 4; ++r) acc[m][n][r] = 0.f;

    for (int t = 0; t < NT; ++t) {
        const int ko = t * 64;
#pragma unroll
        for (int j = 0; j < 4; ++j) gload16(sA[j] + ko, &As[0][0] + dLds[j]);
#pragma unroll
        for (int j = 0; j < 4; ++j) gload16(sB[j] + ko, &Bs[0][0] + dLds[j]);
        __syncthreads();   // compiler drains vmcnt(0) -> staged data visible

#pragma unroll
        for (int kk = 0; kk < 2; ++kk) {
            const int gsw = ((kk * 4 + hi) ^ x7) * 8;
            short8 af[4], bfr[4];
#pragma unroll
            for (int m = 0; m < 4; ++m)
                af[m] = *(const short8*)(&As[wr * 64 + m * 16 + r15][0] + gsw);
#pragma unroll
            for (int n = 0; n < 4; ++n)
                bfr[n] = *(const short8*)(&Bs[wc * 64 + n * 16 + r15][0] + gsw);
            __builtin_amdgcn_s_setprio(1);   // T5: favor GEMM waves over
#pragma unroll
            for (int m = 0; m < 4; ++m)      // co-resident tc2 streaming waves
#pragma unroll
                for (int n = 0; n < 4; ++n)
                    acc[m][n] = __builtin_amdgcn_mfma_f32_16x16x32_bf16(af[m], bfr[n], acc[m][n], 0, 0, 0);
            __builtin_amdgcn_s_setprio(0);
        }
        __syncthreads();   // all reads done before next-iter staging overwrites
    }

    // epilogue: C/D layout col=lane&15, row=(lane>>4)*4+r
    if (PHASE == 1) {
        // stage C-tile (128x128 bf16 = 32 KB) in LDS over dead As/Bs, then
        // write h in coalesced 128B-per-thread bursts (fix 32B-scatter ampl.)
        unsigned short (*Cs)[128] = (unsigned short (*)[128])smem;
#pragma unroll
        for (int n = 0; n < 4; ++n) {
            const int col = wc * 64 + n * 16 + r15;
            const float bv = bias[(size_t)e * N + n0 + col];
#pragma unroll
            for (int m = 0; m < 4; ++m) {
#pragma unroll
                for (int r = 0; r < 4; ++r) {
                    const int row = wr * 64 + m * 16 + hi * 4 + r;
                    const float v = acc[m][n][r] + bv;
                    // tanh-approx gelu == v * sigmoid(1.5957691*(v+0.044715 v^3))
                    const float s = 1.f / (1.f + __expf(-1.5957691216f * (v + 0.044715f * v * v * v)));
                    Cs[row][col] = f2bf(v * s);
                }
            }
        }
        __syncthreads();
        const int row = tid >> 1;
        if (rt * 128 + row < cnt) {     // don't spill into next expert's rows
            const uint4* srcv = (const uint4*)&Cs[row][(tid & 1) * 64];
            uint4* dstv = (uint4*)(h + (size_t)(hrow0 + row) * HID + n0 + (tid & 1) * 64);
#pragma unroll
            for (int p = 0; p < 8; ++p) dstv[p] = srcv[p];
        }
    } else {
#pragma unroll
        for (int n = 0; n < 4; ++n) {
            const int col = n0 + wc * 64 + n * 16 + r15;
            const float bv = (kc == 0) ? bias[(size_t)e * N + col] : 0.f;
#pragma unroll
            for (int m = 0; m < 4; ++m) {
                const int rbase = wr * 64 + m * 16 + hi * 4;
#pragma unroll
                for (int r = 0; r < 4; ++r) {
                    const int row = rbase + r;
                    if (rt * 128 + row < cnt) {
                        const float v = (acc[m][n][r] + bv) * gates_s[row];
                        atomicAdd(&out[(size_t)(rows_s[row] >> 1) * DIM + col], v);
                    }
                }
            }
        }
    }
}

// ---- K1: prep (blocks 0..1023)  ||  transconv W1 (blocks 1024..9215) --------
// Own 9 KB LDS (NOT the 33 KB GEMM union) -> 8 blocks/CU for latency hiding.
__global__ __launch_bounds__(256, 8) void k1_prep_tc1(
    const float* __restrict__ x, const float* __restrict__ Wg,
    const float* __restrict__ bg, int* __restrict__ counts,
    int* __restrict__ rowlist, float* __restrict__ gatelist,
    unsigned short* __restrict__ xb, float* __restrict__ out,
    const float* __restrict__ W1, unsigned short* __restrict__ W1b) {
    __shared__ __align__(16) char smem[TC_SMEM];
    if (blockIdx.x < PREP_BLOCKS)
        prep_body(x, Wg, bg, counts, rowlist, gatelist, xb, out, blockIdx.x);
    else
        transconv_body<DIM, HID>(W1, W1b, blockIdx.x - PREP_BLOCKS, smem);
}

// ---- K3: GEMM1 (blocks 0..2303)  ||  transconv W2 (blocks 2304..10495) ------
__global__ __launch_bounds__(256, 4) void k3_gemm1_tc2(
    const unsigned short* __restrict__ xb, const unsigned short* __restrict__ W1b,
    const float* __restrict__ b1, const int* __restrict__ counts,
    const int* __restrict__ rowlist, const float* __restrict__ gatelist,
    const int* __restrict__ wl1, const int* __restrict__ nw,
    unsigned short* __restrict__ h,
    const float* __restrict__ W2, unsigned short* __restrict__ W2b) {
    __shared__ __align__(16) char smem[SMEM_BYTES];
    if (blockIdx.x < G1_BLOCKS)
        gemm_body<1, 1>(xb, W1b, b1, counts, rowlist, gatelist, wl1, nw,
                        h, nullptr, blockIdx.x, smem);
    else
        transconv_body<HID, DIM>(W2, W2b, blockIdx.x - G1_BLOCKS, smem);
}

// ---- K4: GEMM2 ---------------------------------------------------------------
__global__ __launch_bounds__(256, 4) void k4_gemm2(
    const unsigned short* __restrict__ h, const unsigned short* __restrict__ W2b,
    const float* __restrict__ b2, const int* __restrict__ counts,
    const int* __restrict__ rowlist, const float* __restrict__ gatelist,
    const int* __restrict__ wl2, const int* __restrict__ nw,
    float* __restrict__ out) {
    __shared__ __align__(16) char smem[SMEM_BYTES];
    gemm_body<2, 2>(h, W2b, b2, counts, rowlist, gatelist, wl2, nw,
                    nullptr, out, blockIdx.x, smem);
}

extern "C" void kernel_launch(void* const* d_in, const int* in_sizes, int n_in,
                              void* d_out, int out_size, void* d_ws, size_t ws_size,
                              hipStream_t stream) {
    (void)in_sizes; (void)n_in; (void)out_size; (void)ws_size;
    const float* x  = (const float*)d_in[0];
    const float* Wg = (const float*)d_in[1];
    const float* bg = (const float*)d_in[2];
    const float* W1 = (const float*)d_in[3];
    const float* b1 = (const float*)d_in[4];
    const float* W2 = (const float*)d_in[5];
    const float* b2 = (const float*)d_in[6];
    float* out = (float*)d_out;

    char* ws = (char*)d_ws;
    size_t off = 0;
    auto alloc = [&](size_t bytes) -> void* {
        size_t a = (off + 255) & ~(size_t)255;
        off = a + bytes;
        return (void*)(ws + a);
    };
    int*   counts   = (int*)alloc(NE * sizeof(int));
    int*   nw       = (int*)alloc((2 + NE) * sizeof(int));
    int*   wl1      = (int*)alloc((size_t)MAXT128 * 32 * sizeof(int));
    int*   wl2      = (int*)alloc((size_t)MAXT128 * 16 * sizeof(int));
    int*   rowlist  = (int*)alloc((size_t)NE * T_TOKENS * sizeof(int));
    float* gatelist = (float*)alloc((size_t)NE * T_TOKENS * sizeof(float));
    unsigned short* xb  = (unsigned short*)alloc((size_t)T_TOKENS * DIM * 2);
    unsigned short* h   = (unsigned short*)alloc((size_t)T_TOKENS * TOPK * HID * 2);
    unsigned short* W1b = (unsigned short*)alloc((size_t)NE * DIM * HID * 2);
    unsigned short* W2b = (unsigned short*)alloc((size_t)NE * HID * DIM * 2);
    // total ws use: ~200.4 MB

    hipMemsetAsync(counts, 0, NE * sizeof(int), stream);
    // K1: prep || transconv W1   (9 KB LDS -> 8 blocks/CU)
    k1_prep_tc1<<<PREP_BLOCKS + TC_BLOCKS, 256, 0, stream>>>(
        x, Wg, bg, counts, rowlist, gatelist, xb, out, W1, W1b);
    planner_kernel<<<1, 256, 0, stream>>>(counts, wl1, wl2, nw);
    // K3: GEMM1 || transconv W2  (GEMM1 needs only W1b; tc2 fills stall slots)
    k3_gemm1_tc2<<<G1_BLOCKS + TC_BLOCKS, 256, 0, stream>>>(
        xb, W1b, b1, counts, rowlist, gatelist, wl1, nw, h, W2, W2b);
    // K4: GEMM2 on expert-compacted h (linear A-reads)
    k4_gemm2<<<G2_BLOCKS, 256, 0, stream>>>(
        h, W2b, b2, counts, rowlist, gatelist, wl2, nw, out);
}